// Round 1
// baseline (428.696 us; speedup 1.0000x reference)
//
#include <hip/hip_runtime.h>

// Input:  (16, 1, 2048, 2048) fp32
// Output: low  (16, 1, 1024, 1024) fp32  — LL
//         high (16, 3, 1024, 1024) fp32  — LH, HL, HH
// d_out = [low | high] flat.
//
// Each thread: 2 output pixels (one float4 read per input row, two rows),
// writes float2 to each of the 4 subbands. All accesses coalesced.

#define B   16
#define H   2048
#define W   2048
#define HO  1024
#define WO  1024

__global__ __launch_bounds__(256) void dwt_haar_kernel(
    const float* __restrict__ x, float* __restrict__ out)
{
    // total threads = B * HO * (WO/2) = 16 * 1024 * 512 = 8,388,608
    const unsigned tid = blockIdx.x * blockDim.x + threadIdx.x;
    const int j2 = tid & 511;          // float2 column index [0,512)
    const int i  = (tid >> 9) & 1023;  // output row
    const int b  = tid >> 19;          // batch

    const size_t in_base = (size_t)b * H * W + (size_t)(2 * i) * W + 4 * (size_t)j2;
    const float4 r0 = *(const float4*)(x + in_base);        // a0 b0 a1 b1
    const float4 r1 = *(const float4*)(x + in_base + W);    // c0 d0 c1 d1

    const float a0 = r0.x, b0 = r0.y, a1 = r0.z, b1 = r0.w;
    const float c0 = r1.x, d0 = r1.y, c1 = r1.z, d1 = r1.w;

    const float2 LL = make_float2((a0 + b0 + c0 + d0) * 0.5f,
                                  (a1 + b1 + c1 + d1) * 0.5f);
    const float2 LH = make_float2((a0 + b0 - c0 - d0) * 0.5f,
                                  (a1 + b1 - c1 - d1) * 0.5f);
    const float2 HL = make_float2((a0 - b0 + c0 - d0) * 0.5f,
                                  (a1 - b1 + c1 - d1) * 0.5f);
    const float2 HH = make_float2((a0 - b0 - c0 + d0) * 0.5f,
                                  (a1 - b1 - c1 + d1) * 0.5f);

    const size_t plane = (size_t)HO * WO;          // 1,048,576
    const size_t row_off = (size_t)i * WO;

    float* low  = out;                              // (B,1,HO,WO)
    float* high = out + (size_t)B * plane;          // (B,3,HO,WO)

    ((float2*)(low  + (size_t)b * plane           + row_off))[j2] = LL;
    ((float2*)(high + (size_t)(b * 3 + 0) * plane + row_off))[j2] = LH;
    ((float2*)(high + (size_t)(b * 3 + 1) * plane + row_off))[j2] = HL;
    ((float2*)(high + (size_t)(b * 3 + 2) * plane + row_off))[j2] = HH;
}

extern "C" void kernel_launch(void* const* d_in, const int* in_sizes, int n_in,
                              void* d_out, int out_size, void* d_ws, size_t ws_size,
                              hipStream_t stream) {
    const float* x = (const float*)d_in[0];
    float* out = (float*)d_out;

    const int total_threads = B * HO * (WO / 2);   // 8,388,608
    const int block = 256;
    const int grid = total_threads / block;        // 32,768

    dwt_haar_kernel<<<grid, block, 0, stream>>>(x, out);
}